// Round 1
// baseline (1902.954 us; speedup 1.0000x reference)
//
#include <hip/hip_runtime.h>

#define NBLK 256
#define TPB  512

__device__ __forceinline__ float fast_tanh(float z) {
    // tanh(z) = 1 - 2/(exp(2z)+1); saturates correctly at +-inf
    float e = __expf(2.0f * z);
    return 1.0f - 2.0f * __builtin_amdgcn_rcpf(e + 1.0f);
}

__device__ __forceinline__ float wave_sum(float v) {
    #pragma unroll
    for (int m = 32; m >= 1; m >>= 1) v += __shfl_xor(v, m, 64);
    return v;
}

// Wave-per-4-samples fused MLP value+grad+HVP kernel.
// Lane l owns vector dims {l, l+64} of every 128-vector; weights in LDS
// with row stride 129 (odd) so both matvec orientations are ~2-way conflicts.
__global__ __launch_bounds__(TPB, 2) void mlp_all_kernel(
    const float* __restrict__ X,
    const float* __restrict__ gW1, const float* __restrict__ gB1,
    const float* __restrict__ gW2, const float* __restrict__ gB2,
    const float* __restrict__ gW3, const float* __restrict__ gB3,
    const float* __restrict__ gW4, const float* __restrict__ gB4,
    float* __restrict__ out, int N)
{
    __shared__ float sW2[128 * 129];
    __shared__ float sW3[128 * 129];
    __shared__ float sW1[3 * 128];
    __shared__ float sW4[128];
    __shared__ float sB1[128];
    __shared__ float sB2[128];
    __shared__ float sB3[128];
    __shared__ float4 stage[(TPB / 64) * 128];

    const int tid = threadIdx.x;
    for (int i = tid; i < 128 * 128; i += TPB) {
        int r = i >> 7, c = i & 127;
        sW2[r * 129 + c] = gW2[i];
        sW3[r * 129 + c] = gW3[i];
    }
    if (tid < 3 * 128) sW1[tid] = gW1[tid];
    if (tid < 128) {
        sW4[tid] = gW4[tid];
        sB1[tid] = gB1[tid];
        sB2[tid] = gB2[tid];
        sB3[tid] = gB3[tid];
    }
    __syncthreads();

    const int lane = tid & 63;
    const int wave = tid >> 6;
    float4* const st = stage + (wave << 7);
    const float b4v = gB4[0];

    const float w1t_a = sW1[lane],       w1t_b = sW1[lane + 64];
    const float w1x_a = sW1[128 + lane], w1x_b = sW1[128 + lane + 64];
    const float w1y_a = sW1[256 + lane], w1y_b = sW1[256 + lane + 64];
    const float b1a = sB1[lane], b1b = sB1[lane + 64];
    const float b2a = sB2[lane], b2b = sB2[lane + 64];
    const float b3a = sB3[lane], b3b = sB3[lane + 64];
    const float w4a = sW4[lane], w4b = sW4[lane + 64];

    // stage 4 samples x 128 dims into per-wave LDS: layout [dim][sample]
    auto stage_vec = [&](const float* va, const float* vb) {
        asm volatile("s_waitcnt lgkmcnt(0)" ::: "memory");  // prior reads done
        st[lane]      = make_float4(va[0], va[1], va[2], va[3]);
        st[lane + 64] = make_float4(vb[0], vb[1], vb[2], vb[3]);
        asm volatile("s_waitcnt lgkmcnt(0)" ::: "memory");  // writes visible
    };

    // z[j] = sum_i v[i] * W[i][j] + b  (lane owns out cols {lane, lane+64})
    auto matvec_out = [&](const float* Wp, float ba, float bb, float* oa, float* ob) {
        float aa0 = ba, aa1 = ba, aa2 = ba, aa3 = ba;
        float ab0 = bb, ab1 = bb, ab2 = bb, ab3 = bb;
        const float* wpa = Wp + lane;
        const float* wpb = Wp + lane + 64;
        #pragma unroll 4
        for (int i = 0; i < 128; i++) {
            float4 hv = st[i];          // uniform-address broadcast read
            float wA = wpa[i * 129];
            float wB = wpb[i * 129];
            aa0 = fmaf(hv.x, wA, aa0); aa1 = fmaf(hv.y, wA, aa1);
            aa2 = fmaf(hv.z, wA, aa2); aa3 = fmaf(hv.w, wA, aa3);
            ab0 = fmaf(hv.x, wB, ab0); ab1 = fmaf(hv.y, wB, ab1);
            ab2 = fmaf(hv.z, wB, ab2); ab3 = fmaf(hv.w, wB, ab3);
        }
        oa[0] = aa0; oa[1] = aa1; oa[2] = aa2; oa[3] = aa3;
        ob[0] = ab0; ob[1] = ab1; ob[2] = ab2; ob[3] = ab3;
    };

    // u[i] = sum_j W[i][j] * v[j]  (lane owns out rows {lane, lane+64})
    auto matvec_in = [&](const float* Wp, float* oa, float* ob) {
        float aa0 = 0.f, aa1 = 0.f, aa2 = 0.f, aa3 = 0.f;
        float ab0 = 0.f, ab1 = 0.f, ab2 = 0.f, ab3 = 0.f;
        const float* rowA = Wp + lane * 129;
        const float* rowB = Wp + (lane + 64) * 129;
        #pragma unroll 4
        for (int j = 0; j < 128; j++) {
            float4 dv = st[j];
            float wA = rowA[j];
            float wB = rowB[j];
            aa0 = fmaf(dv.x, wA, aa0); aa1 = fmaf(dv.y, wA, aa1);
            aa2 = fmaf(dv.z, wA, aa2); aa3 = fmaf(dv.w, wA, aa3);
            ab0 = fmaf(dv.x, wB, ab0); ab1 = fmaf(dv.y, wB, ab1);
            ab2 = fmaf(dv.z, wB, ab2); ab3 = fmaf(dv.w, wB, ab3);
        }
        oa[0] = aa0; oa[1] = aa1; oa[2] = aa2; oa[3] = aa3;
        ob[0] = ab0; ob[1] = ab1; ob[2] = ab2; ob[3] = ab3;
    };

    const int groupsTotal = N >> 2;
    const int gw0 = (blockIdx.x << 3) + wave;
    const int gstep = gridDim.x << 3;

    for (int g = gw0; g < groupsTotal; g += gstep) {
        const int s0 = g << 2;

        float xt[4], xx[4], xy[4];
        #pragma unroll
        for (int s = 0; s < 4; s++) {
            xt[s] = X[(s0 + s) * 3 + 0];
            xx[s] = X[(s0 + s) * 3 + 1];
            xy[s] = X[(s0 + s) * 3 + 2];
        }

        // ---------- forward ----------
        float h1a[4], h1b[4], h2a[4], h2b[4], h3a[4], h3b[4];
        #pragma unroll
        for (int s = 0; s < 4; s++) {
            h1a[s] = fast_tanh(fmaf(xt[s], w1t_a, fmaf(xx[s], w1x_a, fmaf(xy[s], w1y_a, b1a))));
            h1b[s] = fast_tanh(fmaf(xt[s], w1t_b, fmaf(xx[s], w1x_b, fmaf(xy[s], w1y_b, b1b))));
        }

        float ta[4], tb[4];
        stage_vec(h1a, h1b);
        matvec_out(sW2, b2a, b2b, ta, tb);
        #pragma unroll
        for (int s = 0; s < 4; s++) { h2a[s] = fast_tanh(ta[s]); h2b[s] = fast_tanh(tb[s]); }
        stage_vec(h2a, h2b);
        matvec_out(sW3, b3a, b3b, ta, tb);
        #pragma unroll
        for (int s = 0; s < 4; s++) { h3a[s] = fast_tanh(ta[s]); h3b[s] = fast_tanh(tb[s]); }

        // c = h3 . W4 + b4
        {
            float cv0 = wave_sum(fmaf(h3a[0], w4a, h3b[0] * w4b)) + b4v;
            float cv1 = wave_sum(fmaf(h3a[1], w4a, h3b[1] * w4b)) + b4v;
            float cv2 = wave_sum(fmaf(h3a[2], w4a, h3b[2] * w4b)) + b4v;
            float cv3 = wave_sum(fmaf(h3a[3], w4a, h3b[3] * w4b)) + b4v;
            if (lane == 0) {
                out[s0 + 0] = cv0; out[s0 + 1] = cv1; out[s0 + 2] = cv2; out[s0 + 3] = cv3;
            }
        }

        // ---------- backward (gradient) ----------
        float u2a[4], u2b[4], u1a[4], u1b[4];
        #pragma unroll
        for (int s = 0; s < 4; s++) {
            ta[s] = w4a * (1.f - h3a[s] * h3a[s]);   // d3
            tb[s] = w4b * (1.f - h3b[s] * h3b[s]);
        }
        stage_vec(ta, tb);
        matvec_in(sW3, u2a, u2b);                    // u2 = W3 d3
        #pragma unroll
        for (int s = 0; s < 4; s++) {
            ta[s] = u2a[s] * (1.f - h2a[s] * h2a[s]); // d2
            tb[s] = u2b[s] * (1.f - h2b[s] * h2b[s]);
        }
        stage_vec(ta, tb);
        matvec_in(sW2, u1a, u1b);                    // u1 = W2 d2
        {
            float gt[4], gx[4], gy[4];
            #pragma unroll
            for (int s = 0; s < 4; s++) {
                float d1A = u1a[s] * (1.f - h1a[s] * h1a[s]);
                float d1B = u1b[s] * (1.f - h1b[s] * h1b[s]);
                gt[s] = wave_sum(fmaf(d1A, w1t_a, d1B * w1t_b));
                gx[s] = wave_sum(fmaf(d1A, w1x_a, d1B * w1x_b));
                gy[s] = wave_sum(fmaf(d1A, w1y_a, d1B * w1y_b));
            }
            if (lane == 0) {
                #pragma unroll
                for (int s = 0; s < 4; s++) {
                    out[N + s0 + s]     = gt[s];
                    out[2 * N + s0 + s] = gx[s];
                    out[3 * N + s0 + s] = gy[s];
                }
            }
        }

        // ---------- HVPs: forward-over-reverse, dirs e_x (W1 row 1), e_y (row 2) ----------
        #pragma unroll
        for (int dir = 0; dir < 2; dir++) {
            const float wra = dir ? w1y_a : w1x_a;
            const float wrb = dir ? w1y_b : w1x_b;

            float th1a[4], th1b[4], th2a[4], th2b[4], th3a[4], th3b[4];
            float tua[4], tub[4];
            #pragma unroll
            for (int s = 0; s < 4; s++) {
                th1a[s] = (1.f - h1a[s] * h1a[s]) * wra;   // t_h1
                th1b[s] = (1.f - h1b[s] * h1b[s]) * wrb;
            }
            stage_vec(th1a, th1b);
            matvec_out(sW2, 0.f, 0.f, ta, tb);             // t_z2
            #pragma unroll
            for (int s = 0; s < 4; s++) {
                th2a[s] = (1.f - h2a[s] * h2a[s]) * ta[s]; // t_h2
                th2b[s] = (1.f - h2b[s] * h2b[s]) * tb[s];
            }
            stage_vec(th2a, th2b);
            matvec_out(sW3, 0.f, 0.f, ta, tb);             // t_z3
            #pragma unroll
            for (int s = 0; s < 4; s++) {
                th3a[s] = (1.f - h3a[s] * h3a[s]) * ta[s]; // t_h3
                th3b[s] = (1.f - h3b[s] * h3b[s]) * tb[s];
            }
            #pragma unroll
            for (int s = 0; s < 4; s++) {
                ta[s] = w4a * (-2.f * h3a[s] * th3a[s]);   // t_d3
                tb[s] = w4b * (-2.f * h3b[s] * th3b[s]);
            }
            stage_vec(ta, tb);
            matvec_in(sW3, tua, tub);                      // t_u2
            #pragma unroll
            for (int s = 0; s < 4; s++) {                  // t_d2
                ta[s] = tua[s] * (1.f - h2a[s] * h2a[s]) - 2.f * u2a[s] * h2a[s] * th2a[s];
                tb[s] = tub[s] * (1.f - h2b[s] * h2b[s]) - 2.f * u2b[s] * h2b[s] * th2b[s];
            }
            stage_vec(ta, tb);
            matvec_in(sW2, tua, tub);                      // t_u1
            {
                float hv[4];
                #pragma unroll
                for (int s = 0; s < 4; s++) {              // t_d1, project on W1 row r
                    float td1A = tua[s] * (1.f - h1a[s] * h1a[s]) - 2.f * u1a[s] * h1a[s] * th1a[s];
                    float td1B = tub[s] * (1.f - h1b[s] * h1b[s]) - 2.f * u1b[s] * h1b[s] * th1b[s];
                    hv[s] = wave_sum(fmaf(td1A, wra, td1B * wrb));
                }
                if (lane == 0) {
                    const long off = dir ? 5L * N : 4L * N;
                    #pragma unroll
                    for (int s = 0; s < 4; s++) out[off + s0 + s] = hv[s];
                }
            }
        }
    }
}

extern "C" void kernel_launch(void* const* d_in, const int* in_sizes, int n_in,
                              void* d_out, int out_size, void* d_ws, size_t ws_size,
                              hipStream_t stream) {
    const float* X  = (const float*)d_in[0];
    const float* W1 = (const float*)d_in[1];
    const float* B1 = (const float*)d_in[2];
    const float* W2 = (const float*)d_in[3];
    const float* B2 = (const float*)d_in[4];
    const float* W3 = (const float*)d_in[5];
    const float* B3 = (const float*)d_in[6];
    const float* W4 = (const float*)d_in[7];
    const float* B4 = (const float*)d_in[8];
    float* out = (float*)d_out;
    const int N = in_sizes[0] / 3;

    mlp_all_kernel<<<NBLK, TPB, 0, stream>>>(X, W1, B1, W2, B2, W3, B3, W4, B4, out, N);
}

// Round 2
// 342.963 us; speedup vs baseline: 5.5486x; 5.5486x over previous
//
#include <hip/hip_runtime.h>
#include <hip/hip_bf16.h>

#define TPB   448
#define NWAVE 7
#define NBLK  256

typedef short  short8 __attribute__((ext_vector_type(8)));
typedef float  f32x4  __attribute__((ext_vector_type(4)));
typedef unsigned uint4v __attribute__((ext_vector_type(4)));

__device__ __forceinline__ float fast_tanh(float z) {
    float e = __expf(2.0f * z);
    return 1.0f - 2.0f * __builtin_amdgcn_rcpf(e + 1.0f);
}

__device__ __forceinline__ unsigned pack_bf2(float lo, float hi) {
    __hip_bfloat16 l = __float2bfloat16(lo);
    __hip_bfloat16 h = __float2bfloat16(hi);
    unsigned short ls, hs;
    __builtin_memcpy(&ls, &l, 2);
    __builtin_memcpy(&hs, &h, 2);
    return (unsigned)ls | ((unsigned)hs << 16);
}
__device__ __forceinline__ float bflo(unsigned u) { return __builtin_bit_cast(float, u << 16); }
__device__ __forceinline__ float bfhi(unsigned u) { return __builtin_bit_cast(float, u & 0xffff0000u); }

template<int CTRL>
__device__ __forceinline__ float dpp_add(float v) {
    int s = __builtin_amdgcn_update_dpp(0, __builtin_bit_cast(int, v), CTRL, 0xf, 0xf, true);
    return v + __builtin_bit_cast(float, s);
}
// sum over the 16 lanes of each DPP row; result valid in lane (l&15)==15
__device__ __forceinline__ float rowsum16(float v) {
    v = dpp_add<0x111>(v);  // row_shr:1
    v = dpp_add<0x112>(v);  // row_shr:2
    v = dpp_add<0x114>(v);  // row_shr:4
    v = dpp_add<0x118>(v);  // row_shr:8
    return v;
}

// Stage a 16x128 activation tile (k-permuted layout, XOR-swizzled blocks).
// Lane owns cols c+16*nt (C-frag layout); permuted positions c*8+nt are contiguous.
__device__ __forceinline__ void stage_write(unsigned short* st, int c, int g,
                                            const unsigned p[4][4]) {
    #pragma unroll
    for (int q = 0; q < 4; q++) {
        int s = g * 4 + q;
        uint4v u; u[0] = p[q][0]; u[1] = p[q][1]; u[2] = p[q][2]; u[3] = p[q][3];
        *reinterpret_cast<short8*>(st + s * 128 + ((c ^ (s & 7)) << 3)) =
            __builtin_bit_cast(short8, u);
    }
    asm volatile("" ::: "memory");
}

__device__ __forceinline__ void frag_load(const unsigned short* st, int c, int g,
                                          short8 fa[4]) {
    #pragma unroll
    for (int kk = 0; kk < 4; kk++) {
        int b = (kk * 4 + g) ^ (c & 7);
        fa[kk] = *reinterpret_cast<const short8*>(st + c * 128 + (b << 3));
    }
    asm volatile("" ::: "memory");
}

// Three GEMMs sharing one weight-panel pass (B-frag loaded once per (kk,nt)).
__device__ __forceinline__ void gemm3(const unsigned short* pnl, int c, int g,
                                      const short8 fa0[4], const short8 fa1[4],
                                      const short8 fa2[4],
                                      f32x4 accZ[8], f32x4 accX[8], f32x4 accY[8]) {
    #pragma unroll
    for (int kk = 0; kk < 4; kk++) {
        int b = (kk * 4 + g) ^ (c & 7);
        #pragma unroll
        for (int nt = 0; nt < 8; nt++) {
            const short8 bf = *reinterpret_cast<const short8*>(
                pnl + ((nt * 16 + c) << 7) + (b << 3));
            accZ[nt] = __builtin_amdgcn_mfma_f32_16x16x32_bf16(fa0[kk], bf, accZ[nt], 0, 0, 0);
            accX[nt] = __builtin_amdgcn_mfma_f32_16x16x32_bf16(fa1[kk], bf, accX[nt], 0, 0, 0);
            accY[nt] = __builtin_amdgcn_mfma_f32_16x16x32_bf16(fa2[kk], bf, accY[nt], 0, 0, 0);
        }
    }
}

__device__ __forceinline__ f32x4 splat4(float v) { f32x4 r = {v, v, v, v}; return r; }

__global__ __launch_bounds__(TPB, 2) void mlp_mfma_kernel(
    const float* __restrict__ X,
    const float* __restrict__ gW1, const float* __restrict__ gB1,
    const float* __restrict__ gW2, const float* __restrict__ gB2,
    const float* __restrict__ gW3, const float* __restrict__ gB3,
    const float* __restrict__ gW4, const float* __restrict__ gB4,
    float* __restrict__ out, int N)
{
    // 4 bf16 weight panels (W2f, W2b, W3f, W3b): [n][kp], k-dim permuted + swizzled. 128 KB
    __shared__ alignas(16) unsigned short sPanel[4 * 128 * 128];
    __shared__ alignas(16) unsigned short sStage[NWAVE][16 * 128];   // 28 KB

    const int tid = threadIdx.x;
    // panel[n][kp] = (fwd) W[invperm(kp)][n]  /  (bwd) W[n][invperm(kp)]
    for (int idx = tid; idx < 4 * 128 * 128; idx += TPB) {
        int p = idx >> 14, e = idx & 16383, n = e >> 7, kp = e & 127;
        int k = ((kp & 7) << 4) | (kp >> 3);           // invperm
        const float* Wsrc = (p < 2) ? gW2 : gW3;
        float v = (p & 1) ? Wsrc[n * 128 + k] : Wsrc[k * 128 + n];
        __hip_bfloat16 bv = __float2bfloat16(v);
        unsigned short bits; __builtin_memcpy(&bits, &bv, 2);
        sPanel[(p << 14) + (n << 7) + (((kp >> 3) ^ (n & 7)) << 3) + (kp & 7)] = bits;
    }
    __syncthreads();

    const int lane = tid & 63;
    const int wave = tid >> 6;
    const int c = lane & 15, g = lane >> 4, r0 = g * 4;
    unsigned short* const st = &sStage[wave][0];
    const unsigned short* const pW2f = sPanel;
    const unsigned short* const pW2b = sPanel + (1 << 14);
    const unsigned short* const pW3f = sPanel + (2 << 14);
    const unsigned short* const pW3b = sPanel + (3 << 14);

    // per-lane params at cols f = nt*16 + c
    float w1t[8], w1x[8], w1y[8], w4c[8], b1c[8], b2c[8], b3c[8];
    #pragma unroll
    for (int nt = 0; nt < 8; nt++) {
        int f = nt * 16 + c;
        w1t[nt] = gW1[f]; w1x[nt] = gW1[128 + f]; w1y[nt] = gW1[256 + f];
        w4c[nt] = gW4[f];
        b1c[nt] = gB1[f]; b2c[nt] = gB2[f]; b3c[nt] = gB3[f];
    }
    const float b4 = gB4[0];

    const int tiles = N >> 4;
    for (int t = blockIdx.x * NWAVE + wave; t < tiles; t += NBLK * NWAVE) {
        const int sbase = t << 4;
        float xt[4], xx[4], xy[4];
        #pragma unroll
        for (int q = 0; q < 4; q++) {
            const float* xp = X + (long)(sbase + r0 + q) * 3;
            xt[q] = xp[0]; xx[q] = xp[1]; xy[q] = xp[2];
        }

        unsigned h1p[4][4], h2p[4][4], t2xp[4][4], t2yp[4][4];
        short8 fa0[4], fa1[4], fa2[4];
        f32x4 accZ[8], accX[8], accY[8];

        // ---- Phase A: z1 / h1 and tangent seeds th1 = (1-h1^2) * W1[row r] ----
        {
            unsigned txp[4][4], typ[4][4];
            #pragma unroll
            for (int m = 0; m < 4; m++) {
                int nA = 2 * m, nB = 2 * m + 1;
                #pragma unroll
                for (int q = 0; q < 4; q++) {
                    float zA = fmaf(xt[q], w1t[nA], fmaf(xx[q], w1x[nA], fmaf(xy[q], w1y[nA], b1c[nA])));
                    float zB = fmaf(xt[q], w1t[nB], fmaf(xx[q], w1x[nB], fmaf(xy[q], w1y[nB], b1c[nB])));
                    float hA = fast_tanh(zA), hB = fast_tanh(zB);
                    h1p[q][m] = pack_bf2(hA, hB);
                    float aA = 1.f - hA * hA, aB = 1.f - hB * hB;
                    txp[q][m] = pack_bf2(aA * w1x[nA], aB * w1x[nB]);
                    typ[q][m] = pack_bf2(aA * w1y[nA], aB * w1y[nB]);
                }
            }
            stage_write(st, c, g, h1p); frag_load(st, c, g, fa0);
            stage_write(st, c, g, txp); frag_load(st, c, g, fa1);
            stage_write(st, c, g, typ); frag_load(st, c, g, fa2);
        }

        // ---- Phase B: z2 = h1@W2+b2 ; tz2x ; tz2y ----
        #pragma unroll
        for (int nt = 0; nt < 8; nt++) {
            accZ[nt] = splat4(b2c[nt]); accX[nt] = splat4(0.f); accY[nt] = splat4(0.f);
        }
        gemm3(pW2f, c, g, fa0, fa1, fa2, accZ, accX, accY);

        // ---- Phase C: h2, th2x, th2y ----
        #pragma unroll
        for (int m = 0; m < 4; m++) {
            int nA = 2 * m, nB = 2 * m + 1;
            #pragma unroll
            for (int q = 0; q < 4; q++) {
                float hA = fast_tanh(accZ[nA][q]), hB = fast_tanh(accZ[nB][q]);
                h2p[q][m] = pack_bf2(hA, hB);
                float aA = 1.f - hA * hA, aB = 1.f - hB * hB;
                t2xp[q][m] = pack_bf2(aA * accX[nA][q], aB * accX[nB][q]);
                t2yp[q][m] = pack_bf2(aA * accY[nA][q], aB * accY[nB][q]);
            }
        }
        stage_write(st, c, g, h2p);  frag_load(st, c, g, fa0);
        stage_write(st, c, g, t2xp); frag_load(st, c, g, fa1);
        stage_write(st, c, g, t2yp); frag_load(st, c, g, fa2);

        // ---- Phase D: z3 = h2@W3+b3 ; tz3x ; tz3y ----
        #pragma unroll
        for (int nt = 0; nt < 8; nt++) {
            accZ[nt] = splat4(b3c[nt]); accX[nt] = splat4(0.f); accY[nt] = splat4(0.f);
        }
        gemm3(pW3f, c, g, fa0, fa1, fa2, accZ, accX, accY);

        // ---- Phase E: h3, c-output, d3, td3x, td3y ----
        {
            float cp[4] = {0.f, 0.f, 0.f, 0.f};
            unsigned d3p[4][4], t3xp[4][4], t3yp[4][4];
            #pragma unroll
            for (int m = 0; m < 4; m++) {
                int nA = 2 * m, nB = 2 * m + 1;
                #pragma unroll
                for (int q = 0; q < 4; q++) {
                    float hA = fast_tanh(accZ[nA][q]), hB = fast_tanh(accZ[nB][q]);
                    cp[q] += hA * w4c[nA] + hB * w4c[nB];
                    float aA = 1.f - hA * hA, aB = 1.f - hB * hB;
                    float thxA = aA * accX[nA][q], thxB = aB * accX[nB][q];
                    float thyA = aA * accY[nA][q], thyB = aB * accY[nB][q];
                    d3p[q][m]  = pack_bf2(w4c[nA] * aA, w4c[nB] * aB);
                    t3xp[q][m] = pack_bf2(-2.f * w4c[nA] * hA * thxA, -2.f * w4c[nB] * hB * thxB);
                    t3yp[q][m] = pack_bf2(-2.f * w4c[nA] * hA * thyA, -2.f * w4c[nB] * hB * thyB);
                }
            }
            #pragma unroll
            for (int q = 0; q < 4; q++) {
                float sv = rowsum16(cp[q]);
                if (c == 15) out[sbase + r0 + q] = sv + b4;
            }
            stage_write(st, c, g, d3p);  frag_load(st, c, g, fa0);
            stage_write(st, c, g, t3xp); frag_load(st, c, g, fa1);
            stage_write(st, c, g, t3yp); frag_load(st, c, g, fa2);
        }

        // ---- Phase F: u2 = d3@W3^T ; tu2x ; tu2y ----
        #pragma unroll
        for (int nt = 0; nt < 8; nt++) {
            accZ[nt] = splat4(0.f); accX[nt] = splat4(0.f); accY[nt] = splat4(0.f);
        }
        gemm3(pW3b, c, g, fa0, fa1, fa2, accZ, accX, accY);

        // ---- Phase G: d2, td2x, td2y ----
        {
            unsigned d2p[4][4], tdxp[4][4], tdyp[4][4];
            #pragma unroll
            for (int m = 0; m < 4; m++) {
                int nA = 2 * m, nB = 2 * m + 1;
                #pragma unroll
                for (int q = 0; q < 4; q++) {
                    float u2A = accZ[nA][q], u2B = accZ[nB][q];
                    float hA = bflo(h2p[q][m]), hB = bfhi(h2p[q][m]);
                    float aA = 1.f - hA * hA, aB = 1.f - hB * hB;
                    float thxA = bflo(t2xp[q][m]), thxB = bfhi(t2xp[q][m]);
                    float thyA = bflo(t2yp[q][m]), thyB = bfhi(t2yp[q][m]);
                    d2p[q][m]  = pack_bf2(u2A * aA, u2B * aB);
                    tdxp[q][m] = pack_bf2(accX[nA][q] * aA - 2.f * u2A * hA * thxA,
                                          accX[nB][q] * aB - 2.f * u2B * hB * thxB);
                    tdyp[q][m] = pack_bf2(accY[nA][q] * aA - 2.f * u2A * hA * thyA,
                                          accY[nB][q] * aB - 2.f * u2B * hB * thyB);
                }
            }
            stage_write(st, c, g, d2p);  frag_load(st, c, g, fa0);
            stage_write(st, c, g, tdxp); frag_load(st, c, g, fa1);
            stage_write(st, c, g, tdyp); frag_load(st, c, g, fa2);
        }

        // ---- Phase H: u1 = d2@W2^T ; tu1x ; tu1y ----
        #pragma unroll
        for (int nt = 0; nt < 8; nt++) {
            accZ[nt] = splat4(0.f); accX[nt] = splat4(0.f); accY[nt] = splat4(0.f);
        }
        gemm3(pW2b, c, g, fa0, fa1, fa2, accZ, accX, accY);

        // ---- Phase I: d1, grads, HVP projections ----
        {
            float gtp[4] = {0,0,0,0}, gxp[4] = {0,0,0,0}, gyp[4] = {0,0,0,0};
            float hxp[4] = {0,0,0,0}, hyp[4] = {0,0,0,0};
            #pragma unroll
            for (int m = 0; m < 4; m++) {
                int nA = 2 * m, nB = 2 * m + 1;
                #pragma unroll
                for (int q = 0; q < 4; q++) {
                    float u1A = accZ[nA][q], u1B = accZ[nB][q];
                    float hA = bflo(h1p[q][m]), hB = bfhi(h1p[q][m]);
                    float aA = 1.f - hA * hA, aB = 1.f - hB * hB;
                    float d1A = u1A * aA, d1B = u1B * aB;
                    gtp[q] += d1A * w1t[nA] + d1B * w1t[nB];
                    gxp[q] += d1A * w1x[nA] + d1B * w1x[nB];
                    gyp[q] += d1A * w1y[nA] + d1B * w1y[nB];
                    float thxA = aA * w1x[nA], thxB = aB * w1x[nB];
                    float thyA = aA * w1y[nA], thyB = aB * w1y[nB];
                    float tdxA = accX[nA][q] * aA - 2.f * u1A * hA * thxA;
                    float tdxB = accX[nB][q] * aB - 2.f * u1B * hB * thxB;
                    float tdyA = accY[nA][q] * aA - 2.f * u1A * hA * thyA;
                    float tdyB = accY[nB][q] * aB - 2.f * u1B * hB * thyB;
                    hxp[q] += tdxA * w1x[nA] + tdxB * w1x[nB];
                    hyp[q] += tdyA * w1y[nA] + tdyB * w1y[nB];
                }
            }
            #pragma unroll
            for (int q = 0; q < 4; q++) {
                float s1 = rowsum16(gtp[q]);
                float s2 = rowsum16(gxp[q]);
                float s3 = rowsum16(gyp[q]);
                float s4 = rowsum16(hxp[q]);
                float s5 = rowsum16(hyp[q]);
                if (c == 15) {
                    long s = sbase + r0 + q;
                    out[(long)N + s]     = s1;
                    out[2L * N + s]      = s2;
                    out[3L * N + s]      = s3;
                    out[4L * N + s]      = s4;
                    out[5L * N + s]      = s5;
                }
            }
        }
    }
}

extern "C" void kernel_launch(void* const* d_in, const int* in_sizes, int n_in,
                              void* d_out, int out_size, void* d_ws, size_t ws_size,
                              hipStream_t stream) {
    const float* X  = (const float*)d_in[0];
    const float* W1 = (const float*)d_in[1];
    const float* B1 = (const float*)d_in[2];
    const float* W2 = (const float*)d_in[3];
    const float* B2 = (const float*)d_in[4];
    const float* W3 = (const float*)d_in[5];
    const float* B3 = (const float*)d_in[6];
    const float* W4 = (const float*)d_in[7];
    const float* B4 = (const float*)d_in[8];
    float* out = (float*)d_out;
    const int N = in_sizes[0] / 3;

    mlp_mfma_kernel<<<NBLK, TPB, 0, stream>>>(X, W1, B1, W2, B2, W3, B3, W4, B4, out, N);
}